// Round 3
// baseline (337.705 us; speedup 1.0000x reference)
//
#include <hip/hip_runtime.h>

typedef __attribute__((ext_vector_type(8))) __bf16 bf16x8;
typedef __attribute__((ext_vector_type(4))) float floatx4;

static __device__ __forceinline__ floatx4 mfma16(bf16x8 a, bf16x8 b, floatx4 c) {
  return __builtin_amdgcn_mfma_f32_16x16x32_bf16(a, b, c, 0, 0, 0);
}

static __device__ __forceinline__ unsigned short f2b_bits(float f) {
  __bf16 h = (__bf16)f;
  return __builtin_bit_cast(unsigned short, h);
}

// async global -> LDS, 16B per lane. LDS dest is wave-uniform base + lane*16.
static __device__ __forceinline__ void stage16(const void* g, void* l) {
  __builtin_amdgcn_global_load_lds(
      (__attribute__((address_space(1))) void*)(unsigned long long)g,
      (__attribute__((address_space(3))) void*)(unsigned int)(unsigned long long)l,
      16, 0, 0);
}

// Counted waits + raw barrier (keep compiler from injecting vmcnt(0)).
#define VM6B() asm volatile("s_waitcnt vmcnt(6)\n\ts_barrier" ::: "memory")
#define VM3B() asm volatile("s_waitcnt vmcnt(3)\n\ts_barrier" ::: "memory")
#define VM0B() asm volatile("s_waitcnt vmcnt(0)\n\ts_barrier" ::: "memory")
#define BAR()  asm volatile("s_barrier" ::: "memory")

// ---------------------------------------------------------------- cast + zero lsum
__global__ void cast_kernel(const float4* __restrict__ x, const float4* __restrict__ w,
                            ushort4* __restrict__ xb, ushort4* __restrict__ wb,
                            float* __restrict__ lsum) {
  int i = blockIdx.x * 256 + threadIdx.x;
  if (i < 4194304) {
    float4 v = x[i];
    ushort4 o;
    o.x = f2b_bits(v.x); o.y = f2b_bits(v.y); o.z = f2b_bits(v.z); o.w = f2b_bits(v.w);
    xb[i] = o;
  } else if (i < 4456448) {
    int j = i - 4194304;
    float4 v = w[j];
    ushort4 o;
    o.x = f2b_bits(v.x); o.y = f2b_bits(v.y); o.z = f2b_bits(v.z); o.w = f2b_bits(v.w);
    wb[j] = o;
  } else {
    int j = i - 4456448;
    if (j < 16384) lsum[j] = 0.0f;
  }
}

// ================================================================ 128x256 engine, BK=32
// 512 threads = 8 waves: wr = wid>>2 (2 row-halves of 64), wc = wid&3 (4 col-quarters).
// Per-wave C = 64x64 (acc[4][4] = 64 VGPR). TRIPLE-buffered LDS (72 KiB, 2 blocks/CU):
//   A[3][8][64] bf16x8 chunks + B[3][16][64]; fragment order (row = rg*16+lr, k = lq*8)
//   -> ds_read_b128 conflict-free. Prefetch 2 K-tiles ahead; per-wave 3 loads/tile ->
//   counted vmcnt(6)/(3)/(0), 9 loads in flight steady-state. Raw s_barrier only.

// ---------------------------------------------------------------- fused zT + QK^T/exp
// g in [0,512): zT tiles (16 mt x 4 ntl x 8 b). g in [512,1088): qk tri tiles (72 x 8 b).
// Both read xb; independent outputs -> one dispatch, no serialization between them.
__global__ __launch_bounds__(512, 2) void zq_fused(const unsigned short* __restrict__ xb,
                                                   const unsigned short* __restrict__ wb,
                                                   unsigned short* __restrict__ zT,
                                                   unsigned short* __restrict__ P,
                                                   float* __restrict__ lsum) {
  extern __shared__ bf16x8 lds[];
  bf16x8* ldsA = lds;          // [3][8][64]
  bf16x8* ldsB = lds + 1536;   // [3][16][64]
  const int tid = threadIdx.x, wid = tid >> 6, lane = tid & 63;
  const int wr = wid >> 2, wc = wid & 3, lr = lane & 15, lq = lane >> 4;
  const int g = blockIdx.x;
  const bool is_qk = (g >= 512);

  // ---- operand pointers (identical strides for both parts: rows of 1024 bf16)
  const unsigned short* gA;
  const unsigned short* gB;
  int b, mt, ntl, rt, ct;
  if (!is_qk) {
    b = g & 7;
    const int gg = g >> 3;
    mt = gg >> 2; ntl = gg & 3;
    gA = xb + (size_t)b * 2097152 + (size_t)(mt * 128 + lr) * 1024 + lq * 8;
    gB = wb + (size_t)(ntl * 256 + lr) * 1024 + lq * 8;
  } else {
    const int h = g - 512;
    b = h & 7;
    const int idx = h >> 3;  // 0..71
    int m = (int)((sqrtf(4.0f * idx + 1.0f) - 1.0f) * 0.5f);
    while ((m + 1) * (m + 2) <= idx) ++m;
    while (m * (m + 1) > idx) --m;
    const int rem = idx - m * (m + 1);
    rt = 2 * m + (rem > m);
    ct = rem - (rem > m ? (m + 1) : 0);
    const unsigned short* xbb = xb + (size_t)b * 2097152;
    gA = xbb + (size_t)(rt * 128 + lr) * 1024 + lq * 8;
    gB = xbb + (size_t)(ct * 256 + lr) * 1024 + lq * 8;
  }

  floatx4 acc[4][4] = {};

  // prologue: tiles 0,1 -> bufs 0,1 (6 loads/wave outstanding)
#pragma unroll
  for (int t = 0; t < 2; ++t) {
    stage16(gA + wid * 16384 + t * 32, &ldsA[t * 512 + wid * 64]);
    stage16(gB + wid * 16384 + t * 32, &ldsB[t * 1024 + wid * 64]);
    stage16(gB + (wid + 8) * 16384 + t * 32, &ldsB[t * 1024 + (wid + 8) * 64]);
  }

#pragma unroll
  for (int kt = 0; kt < 32; ++kt) {
    const int cb = kt % 3;
    if (kt + 2 < 32) {
      const int sb = (kt + 2) % 3, k2 = (kt + 2) * 32;
      stage16(gA + wid * 16384 + k2, &ldsA[sb * 512 + wid * 64]);
      stage16(gB + wid * 16384 + k2, &ldsB[sb * 1024 + wid * 64]);
      stage16(gB + (wid + 8) * 16384 + k2, &ldsB[sb * 1024 + (wid + 8) * 64]);
      VM6B();
    } else if (kt + 1 < 32) {
      VM3B();
    } else {
      VM0B();
    }
    bf16x8 a_[4], b_[4];
#pragma unroll
    for (int i = 0; i < 4; ++i) a_[i] = ldsA[cb * 512 + (wr * 4 + i) * 64 + lane];
#pragma unroll
    for (int j = 0; j < 4; ++j) b_[j] = ldsB[cb * 1024 + (wc * 4 + j) * 64 + lane];
#pragma unroll
    for (int i = 0; i < 4; ++i)
#pragma unroll
      for (int j = 0; j < 4; ++j) acc[i][j] = mfma16(a_[i], b_[j], acc[i][j]);
    BAR();
  }

  if (!is_qk) {
    // ---- zT epilogue (cacheable: pv re-reads zT soon)
#pragma unroll
    for (int i = 0; i < 4; ++i) {
      const int m = mt * 128 + wr * 64 + i * 16 + lq * 4;
#pragma unroll
      for (int j = 0; j < 4; ++j) {
        const int e = ntl * 256 + wc * 64 + j * 16 + lr;
        ushort4 o;
        o.x = f2b_bits(acc[i][j][0]); o.y = f2b_bits(acc[i][j][1]);
        o.z = f2b_bits(acc[i][j][2]); o.w = f2b_bits(acc[i][j][3]);
        *(ushort4*)(zT + ((size_t)(b * 1024 + e)) * 2048 + m) = o;
      }
    }
  } else {
    // ---- qk epilogue: exp, tri-packed P (non-temporal), lsum atomics
    const int col128 = 2 * ct + (wc >> 1);
    if (col128 <= rt) {  // strictly-upper 128-tiles have no slot in the tri packing
      const bool diag = (col128 == rt);
      unsigned short* Pt =
          P + ((size_t)b * 136 + (size_t)(rt * (rt + 1) / 2 + col128)) * 16384;
      float* lsb = lsum + b * 2048 + rt * 128;
#pragma unroll
      for (int i = 0; i < 4; ++i) {
        const int row_l = wr * 64 + i * 16 + lq * 4;
        floatx4 rs = {0.0f, 0.0f, 0.0f, 0.0f};
#pragma unroll
        for (int j = 0; j < 4; ++j) {
          const int incol = (wc & 1) * 64 + j * 16 + lr;
#pragma unroll
          for (int v = 0; v < 4; ++v) {
            float p = __expf(acc[i][j][v] * 0.03125f - 44.0f);
            if (diag && incol > row_l + v) p = 0.0f;
            __builtin_nontemporal_store(f2b_bits(p), &Pt[(row_l + v) * 128 + incol]);
            rs[v] += p;
          }
        }
#pragma unroll
        for (int v = 0; v < 4; ++v) {
          float s = rs[v];
          s += __shfl_xor(s, 1);
          s += __shfl_xor(s, 2);
          s += __shfl_xor(s, 4);
          s += __shfl_xor(s, 8);
          if (lr == 0) atomicAdd(&lsb[row_l + v], s);
        }
      }
    }
  }
}

// ---------------------------------------------------------------- O = P @ z, divide by lsum
// Blocks: 8 b x 16 rt x 4 ntl = 512; K = (rt+1)*128 exact (tri-packed P, no zero-fill).
__global__ __launch_bounds__(512, 2) void pv_out(const unsigned short* __restrict__ P,
                                                 const unsigned short* __restrict__ zT,
                                                 const float* __restrict__ lsum,
                                                 float* __restrict__ out) {
  extern __shared__ bf16x8 lds[];
  bf16x8* ldsA = lds;
  bf16x8* ldsB = lds + 1536;
  const int tid = threadIdx.x, wid = tid >> 6, lane = tid & 63;
  const int wr = wid >> 2, wc = wid & 3, lr = lane & 15, lq = lane >> 4;
  const int g = blockIdx.x, b = g & 7, gg = g >> 3;
  const int rt = 15 - (gg >> 2), ntl = gg & 3;  // long K first
  const int NKT = (rt + 1) * 4;                 // BK=32 tiles: 4..64

  const unsigned short* pA = P + (size_t)b * 136 * 16384 +
                             (size_t)(rt * (rt + 1) / 2) * 16384 + lr * 128 + lq * 8;
  const unsigned short* gB =
      zT + (size_t)b * 2097152 + ((size_t)(ntl * 256) + lr) * 2048 + lq * 8;
  floatx4 acc[4][4] = {};

#pragma unroll
  for (int t = 0; t < 2; ++t) {
    stage16(pA + wid * 2048 + (t >> 2) * 16384 + (t & 3) * 32, &ldsA[t * 512 + wid * 64]);
    stage16(gB + wid * 32768 + t * 32, &ldsB[t * 1024 + wid * 64]);
    stage16(gB + (wid + 8) * 32768 + t * 32, &ldsB[t * 1024 + (wid + 8) * 64]);
  }

  int cb = 0, sb = 2;
  for (int kt = 0; kt < NKT; ++kt) {
    if (kt + 2 < NKT) {
      const int k2 = kt + 2;
      stage16(pA + wid * 2048 + (k2 >> 2) * 16384 + (k2 & 3) * 32,
              &ldsA[sb * 512 + wid * 64]);
      stage16(gB + wid * 32768 + k2 * 32, &ldsB[sb * 1024 + wid * 64]);
      stage16(gB + (wid + 8) * 32768 + k2 * 32, &ldsB[sb * 1024 + (wid + 8) * 64]);
      VM6B();
    } else if (kt + 1 < NKT) {
      VM3B();
    } else {
      VM0B();
    }
    bf16x8 a_[4], b_[4];
#pragma unroll
    for (int i = 0; i < 4; ++i) a_[i] = ldsA[cb * 512 + (wr * 4 + i) * 64 + lane];
#pragma unroll
    for (int j = 0; j < 4; ++j) b_[j] = ldsB[cb * 1024 + (wc * 4 + j) * 64 + lane];
#pragma unroll
    for (int i = 0; i < 4; ++i)
#pragma unroll
      for (int j = 0; j < 4; ++j) acc[i][j] = mfma16(a_[i], b_[j], acc[i][j]);
    BAR();
    cb = (cb == 2) ? 0 : cb + 1;
    sb = (sb == 2) ? 0 : sb + 1;
  }

  const float* lsb = lsum + b * 2048 + rt * 128;
  float* outb = out + (size_t)b * 2097152;
#pragma unroll
  for (int i = 0; i < 4; ++i) {
    const int row_l = wr * 64 + i * 16 + lq * 4;
    floatx4 linv;
#pragma unroll
    for (int v = 0; v < 4; ++v) linv[v] = 1.0f / lsb[row_l + v];
#pragma unroll
    for (int j = 0; j < 4; ++j) {
      const int col = ntl * 256 + wc * 64 + j * 16 + lr;
#pragma unroll
      for (int v = 0; v < 4; ++v)
        __builtin_nontemporal_store(acc[i][j][v] * linv[v],
                                    &outb[(size_t)(rt * 128 + row_l + v) * 1024 + col]);
    }
  }
}

// ---------------------------------------------------------------- launcher
extern "C" void kernel_launch(void* const* d_in, const int* in_sizes, int n_in,
                              void* d_out, int out_size, void* d_ws, size_t ws_size,
                              hipStream_t stream) {
  const float* x = (const float*)d_in[0];  // [8][2048][1024]
  const float* W = (const float*)d_in[1];  // [1024][1024]
  float* out = (float*)d_out;              // [8][2048][1024]
  char* ws = (char*)d_ws;
  unsigned short* xb = (unsigned short*)ws;                          // 32 MiB bf16 x
  unsigned short* zT = (unsigned short*)(ws + 33554432ull);          // 32 MiB bf16 z^T
  unsigned short* P  = (unsigned short*)(ws + 67108864ull);          // 34 MiB packed tri P
  unsigned short* wb = (unsigned short*)(ws + 67108864ull + 35651584ull + 65536ull); // 2 MiB
  float* lsum = (float*)(ws + 67108864ull + 35651584ull);            // 64 KiB row sums

  static bool attr_done = false;
  if (!attr_done) {
    (void)hipFuncSetAttribute(reinterpret_cast<const void*>(zq_fused),
                              hipFuncAttributeMaxDynamicSharedMemorySize, 73728);
    (void)hipFuncSetAttribute(reinterpret_cast<const void*>(pv_out),
                              hipFuncAttributeMaxDynamicSharedMemorySize, 73728);
    attr_done = true;
  }

  cast_kernel<<<17472, 256, 0, stream>>>((const float4*)x, (const float4*)W,
                                         (ushort4*)xb, (ushort4*)wb, lsum);
  zq_fused<<<1088, 512, 73728, stream>>>(xb, wb, zT, P, lsum);
  pv_out<<<512, 512, 73728, stream>>>(P, zT, lsum, out);
}

// Round 4
// 229.933 us; speedup vs baseline: 1.4687x; 1.4687x over previous
//
#include <hip/hip_runtime.h>

typedef __attribute__((ext_vector_type(8))) __bf16 bf16x8;
typedef __attribute__((ext_vector_type(4))) float floatx4;

static __device__ __forceinline__ floatx4 mfma16(bf16x8 a, bf16x8 b, floatx4 c) {
  return __builtin_amdgcn_mfma_f32_16x16x32_bf16(a, b, c, 0, 0, 0);
}

static __device__ __forceinline__ unsigned short f2b_bits(float f) {
  __bf16 h = (__bf16)f;
  return __builtin_bit_cast(unsigned short, h);
}

// async global -> LDS, 16B per lane. LDS dest is wave-uniform base + lane*16.
static __device__ __forceinline__ void stage16(const void* g, void* l) {
  __builtin_amdgcn_global_load_lds(
      (__attribute__((address_space(1))) void*)(unsigned long long)g,
      (__attribute__((address_space(3))) void*)(unsigned int)(unsigned long long)l,
      16, 0, 0);
}

// Counted waits + raw barrier (keep compiler from injecting vmcnt(0)).
#define VM6B() asm volatile("s_waitcnt vmcnt(6)\n\ts_barrier" ::: "memory")
#define VM3B() asm volatile("s_waitcnt vmcnt(3)\n\ts_barrier" ::: "memory")
#define VM0B() asm volatile("s_waitcnt vmcnt(0)\n\ts_barrier" ::: "memory")
#define BAR()  asm volatile("s_barrier" ::: "memory")

// ================================================================ chunked layouts
// All staged operands live in "fragment-chunk" order: a chunk is 1 KiB = the exact
// bytes of one LDS chunk [16 rows x 32 k], slot l (16B) = (row l&15, kgroup l>>4).
// Staging is then base + chunk*1024 + lane*16: every global_load_lds reads 1 KiB
// CONTIGUOUS (16 consecutive cache lines -> no L2-channel aliasing), vs the old
// 16x64B segments at 2-4 KiB power-of-2 stride (theory: channel-serialized ~10 B/cyc/CU).
//   xb_c: per batch [rowblk 128][kblk 32] chunks (4096 chunks = 4 MiB)
//   wb_c: [rowblk 64][kblk 32] chunks (2048 chunks = 2 MiB)
//   zT_c: per batch [eblk 64][sblk 64] chunks (4096 chunks = 4 MiB)
//   P:    tri-packed 128x128 tiles, each tile = [qblk 8][kblk 4] chunks (32 KiB)

// ---------------------------------------------------------------- cast + zero lsum
// One thread = one 16B chunk-slot (8 elems). Writes are perfectly linear (idx = i*8).
__global__ void cast_kernel(const float4* __restrict__ x, const float4* __restrict__ w,
                            ushort4* __restrict__ xb, ushort4* __restrict__ wb,
                            float* __restrict__ lsum) {
  int i = blockIdx.x * 256 + threadIdx.x;
  if (i < 2097152) {  // x: 16384 rows x 1024
    const int c = i >> 6, s = i & 63;
    const int R = (c >> 5) * 16 + (s & 15);      // global row (batch-major)
    const int kg = (c & 31) * 4 + (s >> 4);      // k-group of 8
    float4 v0 = x[R * 256 + kg * 2];
    float4 v1 = x[R * 256 + kg * 2 + 1];
    ushort4 o0, o1;
    o0.x = f2b_bits(v0.x); o0.y = f2b_bits(v0.y); o0.z = f2b_bits(v0.z); o0.w = f2b_bits(v0.w);
    o1.x = f2b_bits(v1.x); o1.y = f2b_bits(v1.y); o1.z = f2b_bits(v1.z); o1.w = f2b_bits(v1.w);
    xb[i * 2] = o0; xb[i * 2 + 1] = o1;
  } else if (i < 2228224) {  // W: 1024 x 1024
    const int i2 = i - 2097152;
    const int c = i2 >> 6, s = i2 & 63;
    const int R = (c >> 5) * 16 + (s & 15);
    const int kg = (c & 31) * 4 + (s >> 4);
    float4 v0 = w[R * 256 + kg * 2];
    float4 v1 = w[R * 256 + kg * 2 + 1];
    ushort4 o0, o1;
    o0.x = f2b_bits(v0.x); o0.y = f2b_bits(v0.y); o0.z = f2b_bits(v0.z); o0.w = f2b_bits(v0.w);
    o1.x = f2b_bits(v1.x); o1.y = f2b_bits(v1.y); o1.z = f2b_bits(v1.z); o1.w = f2b_bits(v1.w);
    wb[i2 * 2] = o0; wb[i2 * 2 + 1] = o1;
  } else {
    const int j = i - 2228224;
    if (j < 16384) lsum[j] = 0.0f;
  }
}

// ================================================================ 128x256 engine, BK=32
// 512 threads = 8 waves: wr = wid>>2 (2 row-halves of 64), wc = wid&3 (4 col-quarters).
// Triple-buffered LDS (72 KiB, 2 blocks/CU), prefetch 2 K-tiles, counted vmcnt(6/3/0).
// LDS chunk content identical to rounds 0-3 (verified); only GLOBAL placement changed.

// ---------------------------------------------------------------- fused zT + QK^T/exp
__global__ __launch_bounds__(512, 2) void zq_fused(const unsigned short* __restrict__ xb,
                                                   const unsigned short* __restrict__ wb,
                                                   unsigned short* __restrict__ zT,
                                                   unsigned short* __restrict__ P,
                                                   float* __restrict__ lsum) {
  extern __shared__ bf16x8 lds[];
  bf16x8* ldsA = lds;          // [3][8][64]
  bf16x8* ldsB = lds + 1536;   // [3][16][64]
  const int tid = threadIdx.x, wid = tid >> 6, lane = tid & 63;
  const int wr = wid >> 2, wc = wid & 3, lr = lane & 15, lq = lane >> 4;
  const int g = blockIdx.x;
  const bool is_qk = (g >= 512);

  // per-wave chunk sources: gA/gB point at (chunk row-block base + lane*16B)
  const unsigned short* gA;  // + kt*512 per K-tile
  const unsigned short* gB0; // + kt*512
  const unsigned short* gB1; // + kt*512
  int b, mt, ntl, rt, ct;
  if (!is_qk) {
    b = g & 7;
    const int gg = g >> 3;
    mt = gg >> 2; ntl = gg & 3;
    gA = xb + ((size_t)b * 4096 + (mt * 8 + wid) * 32) * 512 + lane * 8;
    gB0 = wb + (size_t)((ntl * 16 + wid) * 32) * 512 + lane * 8;
    gB1 = wb + (size_t)((ntl * 16 + wid + 8) * 32) * 512 + lane * 8;
  } else {
    const int h = g - 512;
    b = h & 7;
    const int idx = h >> 3;  // 0..71
    int m = (int)((sqrtf(4.0f * idx + 1.0f) - 1.0f) * 0.5f);
    while ((m + 1) * (m + 2) <= idx) ++m;
    while (m * (m + 1) > idx) --m;
    const int rem = idx - m * (m + 1);
    rt = 2 * m + (rem > m);
    ct = rem - (rem > m ? (m + 1) : 0);
    gA = xb + ((size_t)b * 4096 + (rt * 8 + wid) * 32) * 512 + lane * 8;
    gB0 = xb + ((size_t)b * 4096 + (ct * 16 + wid) * 32) * 512 + lane * 8;
    gB1 = xb + ((size_t)b * 4096 + (ct * 16 + wid + 8) * 32) * 512 + lane * 8;
  }

  floatx4 acc[4][4] = {};

#pragma unroll
  for (int t = 0; t < 2; ++t) {
    stage16(gA + t * 512, &ldsA[t * 512 + wid * 64]);
    stage16(gB0 + t * 512, &ldsB[t * 1024 + wid * 64]);
    stage16(gB1 + t * 512, &ldsB[t * 1024 + (wid + 8) * 64]);
  }

#pragma unroll
  for (int kt = 0; kt < 32; ++kt) {
    const int cb = kt % 3;
    if (kt + 2 < 32) {
      const int sb = (kt + 2) % 3;
      stage16(gA + (kt + 2) * 512, &ldsA[sb * 512 + wid * 64]);
      stage16(gB0 + (kt + 2) * 512, &ldsB[sb * 1024 + wid * 64]);
      stage16(gB1 + (kt + 2) * 512, &ldsB[sb * 1024 + (wid + 8) * 64]);
      VM6B();
    } else if (kt + 1 < 32) {
      VM3B();
    } else {
      VM0B();
    }
    bf16x8 a_[4], b_[4];
#pragma unroll
    for (int i = 0; i < 4; ++i) a_[i] = ldsA[cb * 512 + (wr * 4 + i) * 64 + lane];
#pragma unroll
    for (int j = 0; j < 4; ++j) b_[j] = ldsB[cb * 1024 + (wc * 4 + j) * 64 + lane];
#pragma unroll
    for (int i = 0; i < 4; ++i)
#pragma unroll
      for (int j = 0; j < 4; ++j) acc[i][j] = mfma16(a_[i], b_[j], acc[i][j]);
    BAR();
  }

  if (!is_qk) {
    // ---- zT epilogue into chunked zT_c: elem (e,s) -> chunk (e>>4)*64+(s>>5),
    // off = ((s>>3)&3)*128 + (e&15)*8 + (s&7); v (s0..s0+3) contiguous, 8B aligned.
#pragma unroll
    for (int i = 0; i < 4; ++i) {
      const int s0 = mt * 128 + wr * 64 + i * 16 + lq * 4;
      const int s5 = s0 >> 5, s3 = (s0 >> 3) & 3, s7 = s0 & 7;
#pragma unroll
      for (int j = 0; j < 4; ++j) {
        const int e4 = ntl * 16 + wc * 4 + j;  // e>>4 (e&15 = lr)
        ushort4 o;
        o.x = f2b_bits(acc[i][j][0]); o.y = f2b_bits(acc[i][j][1]);
        o.z = f2b_bits(acc[i][j][2]); o.w = f2b_bits(acc[i][j][3]);
        *(ushort4*)(zT + ((size_t)b * 4096 + e4 * 64 + s5) * 512 + s3 * 128 + lr * 8 + s7) = o;
      }
    }
  } else {
    // ---- qk epilogue: exp, tri-packed chunked P, lsum atomics
    const int col128 = 2 * ct + (wc >> 1);
    if (col128 <= rt) {
      const bool diag = (col128 == rt);
      unsigned short* Pt =
          P + ((size_t)b * 136 + (size_t)(rt * (rt + 1) / 2 + col128)) * 16384;
      float* lsb = lsum + b * 2048 + rt * 128;
#pragma unroll
      for (int i = 0; i < 4; ++i) {
        const int row_l = wr * 64 + i * 16 + lq * 4;
        floatx4 rs = {0.0f, 0.0f, 0.0f, 0.0f};
#pragma unroll
        for (int j = 0; j < 4; ++j) {
          const int incol = (wc & 1) * 64 + j * 16 + lr;
          // chunk = (q>>4)*4 + (incol>>5); off = ((incol>>3)&3)*128 + (q&15)*8 + (incol&7)
          const int cbase = ((wr * 4 + i) * 4 + (wc & 1) * 2 + (j >> 1)) * 512 +
                            ((j * 2 + (lr >> 3)) & 3) * 128 + (lr & 7);
#pragma unroll
          for (int v = 0; v < 4; ++v) {
            float p = __expf(acc[i][j][v] * 0.03125f - 44.0f);
            if (diag && incol > row_l + v) p = 0.0f;
            Pt[cbase + (lq * 4 + v) * 8] = f2b_bits(p);
            rs[v] += p;
          }
        }
#pragma unroll
        for (int v = 0; v < 4; ++v) {
          float s = rs[v];
          s += __shfl_xor(s, 1);
          s += __shfl_xor(s, 2);
          s += __shfl_xor(s, 4);
          s += __shfl_xor(s, 8);
          if (lr == 0) atomicAdd(&lsb[row_l + v], s);
        }
      }
    }
  }
}

// ---------------------------------------------------------------- O = P @ z, divide by lsum
__global__ __launch_bounds__(512, 2) void pv_out(const unsigned short* __restrict__ P,
                                                 const unsigned short* __restrict__ zT,
                                                 const float* __restrict__ lsum,
                                                 float* __restrict__ out) {
  extern __shared__ bf16x8 lds[];
  bf16x8* ldsA = lds;
  bf16x8* ldsB = lds + 1536;
  const int tid = threadIdx.x, wid = tid >> 6, lane = tid & 63;
  const int wr = wid >> 2, wc = wid & 3, lr = lane & 15, lq = lane >> 4;
  const int g = blockIdx.x, b = g & 7, gg = g >> 3;
  const int rt = 15 - (gg >> 2), ntl = gg & 3;  // long K first
  const int NKT = (rt + 1) * 4;                 // BK=32 tiles: 4..64

  // A: P tiles (tri-packed, chunked): kt -> tile tri+(kt>>2), chunk wid*4+(kt&3)
  const unsigned short* pA =
      P + ((size_t)b * 136 + (size_t)(rt * (rt + 1) / 2)) * 16384 + (size_t)wid * 2048 + lane * 8;
  // B: zT_c chunks (eblk = ntl*16 + w', sblk = kt)
  const unsigned short* gB0 = zT + ((size_t)b * 4096 + (ntl * 16 + wid) * 64) * 512 + lane * 8;
  const unsigned short* gB1 =
      zT + ((size_t)b * 4096 + (ntl * 16 + wid + 8) * 64) * 512 + lane * 8;
  floatx4 acc[4][4] = {};

#pragma unroll
  for (int t = 0; t < 2; ++t) {
    stage16(pA + (t >> 2) * 16384 + (t & 3) * 512, &ldsA[t * 512 + wid * 64]);
    stage16(gB0 + t * 512, &ldsB[t * 1024 + wid * 64]);
    stage16(gB1 + t * 512, &ldsB[t * 1024 + (wid + 8) * 64]);
  }

  int cb = 0, sb = 2;
  for (int kt = 0; kt < NKT; ++kt) {
    if (kt + 2 < NKT) {
      const int k2 = kt + 2;
      stage16(pA + (k2 >> 2) * 16384 + (k2 & 3) * 512, &ldsA[sb * 512 + wid * 64]);
      stage16(gB0 + k2 * 512, &ldsB[sb * 1024 + wid * 64]);
      stage16(gB1 + k2 * 512, &ldsB[sb * 1024 + (wid + 8) * 64]);
      VM6B();
    } else if (kt + 1 < NKT) {
      VM3B();
    } else {
      VM0B();
    }
    bf16x8 a_[4], b_[4];
#pragma unroll
    for (int i = 0; i < 4; ++i) a_[i] = ldsA[cb * 512 + (wr * 4 + i) * 64 + lane];
#pragma unroll
    for (int j = 0; j < 4; ++j) b_[j] = ldsB[cb * 1024 + (wc * 4 + j) * 64 + lane];
#pragma unroll
    for (int i = 0; i < 4; ++i)
#pragma unroll
      for (int j = 0; j < 4; ++j) acc[i][j] = mfma16(a_[i], b_[j], acc[i][j]);
    BAR();
    cb = (cb == 2) ? 0 : cb + 1;
    sb = (sb == 2) ? 0 : sb + 1;
  }

  const float* lsb = lsum + b * 2048 + rt * 128;
  float* outb = out + (size_t)b * 2097152;
#pragma unroll
  for (int i = 0; i < 4; ++i) {
    const int row_l = wr * 64 + i * 16 + lq * 4;
    floatx4 linv;
#pragma unroll
    for (int v = 0; v < 4; ++v) linv[v] = 1.0f / lsb[row_l + v];
#pragma unroll
    for (int j = 0; j < 4; ++j) {
      const int col = ntl * 256 + wc * 64 + j * 16 + lr;
#pragma unroll
      for (int v = 0; v < 4; ++v)
        __builtin_nontemporal_store(acc[i][j][v] * linv[v],
                                    &outb[(size_t)(rt * 128 + row_l + v) * 1024 + col]);
    }
  }
}

// ---------------------------------------------------------------- launcher
extern "C" void kernel_launch(void* const* d_in, const int* in_sizes, int n_in,
                              void* d_out, int out_size, void* d_ws, size_t ws_size,
                              hipStream_t stream) {
  const float* x = (const float*)d_in[0];  // [8][2048][1024]
  const float* W = (const float*)d_in[1];  // [1024][1024]
  float* out = (float*)d_out;              // [8][2048][1024]
  char* ws = (char*)d_ws;
  unsigned short* xb = (unsigned short*)ws;                          // 32 MiB chunked x
  unsigned short* zT = (unsigned short*)(ws + 33554432ull);          // 32 MiB chunked z^T
  unsigned short* P  = (unsigned short*)(ws + 67108864ull);          // 34 MiB tri P (chunked tiles)
  unsigned short* wb = (unsigned short*)(ws + 67108864ull + 35651584ull + 65536ull); // 2 MiB
  float* lsum = (float*)(ws + 67108864ull + 35651584ull);            // 64 KiB row sums

  static bool attr_done = false;
  if (!attr_done) {
    (void)hipFuncSetAttribute(reinterpret_cast<const void*>(zq_fused),
                              hipFuncAttributeMaxDynamicSharedMemorySize, 73728);
    (void)hipFuncSetAttribute(reinterpret_cast<const void*>(pv_out),
                              hipFuncAttributeMaxDynamicSharedMemorySize, 73728);
    attr_done = true;
  }

  cast_kernel<<<8768, 256, 0, stream>>>((const float4*)x, (const float4*)W,
                                        (ushort4*)xb, (ushort4*)wb, lsum);
  zq_fused<<<1088, 512, 73728, stream>>>(xb, wb, zT, P, lsum);
  pv_out<<<512, 512, 73728, stream>>>(P, zT, lsum, out);
}

// Round 5
// 229.468 us; speedup vs baseline: 1.4717x; 1.0020x over previous
//
#include <hip/hip_runtime.h>

typedef __attribute__((ext_vector_type(8))) __bf16 bf16x8;
typedef __attribute__((ext_vector_type(4))) float floatx4;

static __device__ __forceinline__ floatx4 mfma16(bf16x8 a, bf16x8 b, floatx4 c) {
  return __builtin_amdgcn_mfma_f32_16x16x32_bf16(a, b, c, 0, 0, 0);
}

static __device__ __forceinline__ unsigned short f2b_bits(float f) {
  __bf16 h = (__bf16)f;
  return __builtin_bit_cast(unsigned short, h);
}

// async global -> LDS, 16B per lane. LDS dest is wave-uniform base + lane*16.
static __device__ __forceinline__ void stage16(const void* g, void* l) {
  __builtin_amdgcn_global_load_lds(
      (__attribute__((address_space(1))) void*)(unsigned long long)g,
      (__attribute__((address_space(3))) void*)(unsigned int)(unsigned long long)l,
      16, 0, 0);
}

// Counted waits + raw barrier (keep compiler from injecting vmcnt(0)).
#define VM6B() asm volatile("s_waitcnt vmcnt(6)\n\ts_barrier" ::: "memory")
#define VM3B() asm volatile("s_waitcnt vmcnt(3)\n\ts_barrier" ::: "memory")
#define VM0B() asm volatile("s_waitcnt vmcnt(0)\n\ts_barrier" ::: "memory")
#define BAR()  asm volatile("s_barrier" ::: "memory")

// ================================================================ chunked layouts
// All staged operands live in "fragment-chunk" order: a chunk is 1 KiB = the exact
// bytes of one LDS chunk [16 rows x 32 k], slot l (16B) = (row l&15, kgroup l>>4).
// Staging reads are 1 KiB fully contiguous -> no L2-channel aliasing (round-4 win:
// MfmaUtil 20->40%).
//   xb_c: stripe (16 rows) st = gl_row>>4 -> chunks st*32 + kblk   (32 MiB)
//   wb_c: same with stripe (R>>4)                                   (2 MiB)
//   zT_c: per batch [eblk 64][sblk 64] chunks                       (32 MiB)
//   P:    tri-packed 128x128 tiles, each tile = [qblk 8][kblk 4] chunks (34 MiB)

// ---------------------------------------------------------------- cast (LDS transpose) + zero lsum
// Block = one 16-row stripe: coalesced f32 reads (1 KiB/wave) -> bf16 into swizzled
// LDS (byte ^= (row&7)<<4) -> b128 LDS reads (uniform 8 lanes/bank-group = b128
// minimum) -> fully contiguous 1 KiB/wave chunk writes.
__global__ __launch_bounds__(256) void cast_kernel(const float4* __restrict__ x,
                                                   const float4* __restrict__ w,
                                                   uint4* __restrict__ xb,
                                                   uint4* __restrict__ wb,
                                                   float4* __restrict__ lsum) {
  __shared__ unsigned char sl[32768];  // 16 rows x 2048 B (swizzled)
  const int st = blockIdx.x, tid = threadIdx.x;
  if (st < 1088) {
    const float4* src = (st < 1024) ? x + (size_t)st * 4096 : w + (size_t)(st - 1024) * 4096;
    uint4* dst = (st < 1024) ? xb + (size_t)st * 2048 : wb + (size_t)(st - 1024) * 2048;
#pragma unroll
    for (int it = 0; it < 16; ++it) {
      const int row = it, c4 = (it * 256 + tid) & 255;  // idx = it*256+tid; row=idx>>8
      float4 v = src[row * 256 + c4];
      ushort4 o;
      o.x = f2b_bits(v.x); o.y = f2b_bits(v.y); o.z = f2b_bits(v.z); o.w = f2b_bits(v.w);
      *(ushort4*)(sl + row * 2048 + ((c4 * 8) ^ ((row & 7) << 4))) = o;
    }
    __syncthreads();
#pragma unroll
    for (int it = 0; it < 8; ++it) {
      const int o = it * 4096 + tid * 16;
      const int c = o >> 10, l = (o >> 4) & 63;
      const int row = l & 15, kg = l >> 4;
      uint4 v = *(const uint4*)(sl + row * 2048 + ((c * 64 + kg * 16) ^ ((row & 7) << 4)));
      dst[o >> 4] = v;
    }
  } else {
    const float4 z = {0.0f, 0.0f, 0.0f, 0.0f};
#pragma unroll
    for (int it = 0; it < 4; ++it) lsum[(st - 1088) * 1024 + it * 256 + tid] = z;
  }
}

// ================================================================ 128x256 engine, BK=32
// 512 threads = 8 waves: wr = wid>>2 (2 row-halves of 64), wc = wid&3 (4 col-quarters).
// Triple-buffered LDS (72 KiB, 2 blocks/CU), prefetch 2 K-tiles, counted vmcnt(6/3/0).

// ---------------------------------------------------------------- fused zT + QK^T/exp
__global__ __launch_bounds__(512, 2) void zq_fused(const unsigned short* __restrict__ xb,
                                                   const unsigned short* __restrict__ wb,
                                                   unsigned short* __restrict__ zT,
                                                   unsigned short* __restrict__ P,
                                                   float* __restrict__ lsum) {
  extern __shared__ bf16x8 lds[];
  bf16x8* ldsA = lds;          // [3][8][64]
  bf16x8* ldsB = lds + 1536;   // [3][16][64]
  const int tid = threadIdx.x, wid = tid >> 6, lane = tid & 63;
  const int wr = wid >> 2, wc = wid & 3, lr = lane & 15, lq = lane >> 4;
  const int g = blockIdx.x;
  const bool is_qk = (g >= 512);

  // per-wave chunk sources: gA/gB point at (chunk row-block base + lane*16B)
  const unsigned short* gA;  // + kt*512 per K-tile
  const unsigned short* gB0; // + kt*512
  const unsigned short* gB1; // + kt*512
  int b, mt, ntl, rt, ct;
  if (!is_qk) {
    b = g & 7;
    const int gg = g >> 3;
    mt = gg >> 2; ntl = gg & 3;
    gA = xb + ((size_t)b * 4096 + (mt * 8 + wid) * 32) * 512 + lane * 8;
    gB0 = wb + (size_t)((ntl * 16 + wid) * 32) * 512 + lane * 8;
    gB1 = wb + (size_t)((ntl * 16 + wid + 8) * 32) * 512 + lane * 8;
  } else {
    const int h = g - 512;
    b = h & 7;
    const int idx = h >> 3;  // 0..71
    int m = (int)((sqrtf(4.0f * idx + 1.0f) - 1.0f) * 0.5f);
    while ((m + 1) * (m + 2) <= idx) ++m;
    while (m * (m + 1) > idx) --m;
    const int rem = idx - m * (m + 1);
    rt = 2 * m + (rem > m);
    ct = rem - (rem > m ? (m + 1) : 0);
    gA = xb + ((size_t)b * 4096 + (rt * 8 + wid) * 32) * 512 + lane * 8;
    gB0 = xb + ((size_t)b * 4096 + (ct * 16 + wid) * 32) * 512 + lane * 8;
    gB1 = xb + ((size_t)b * 4096 + (ct * 16 + wid + 8) * 32) * 512 + lane * 8;
  }

  floatx4 acc[4][4] = {};

#pragma unroll
  for (int t = 0; t < 2; ++t) {
    stage16(gA + t * 512, &ldsA[t * 512 + wid * 64]);
    stage16(gB0 + t * 512, &ldsB[t * 1024 + wid * 64]);
    stage16(gB1 + t * 512, &ldsB[t * 1024 + (wid + 8) * 64]);
  }

#pragma unroll
  for (int kt = 0; kt < 32; ++kt) {
    const int cb = kt % 3;
    if (kt + 2 < 32) {
      const int sb = (kt + 2) % 3;
      stage16(gA + (kt + 2) * 512, &ldsA[sb * 512 + wid * 64]);
      stage16(gB0 + (kt + 2) * 512, &ldsB[sb * 1024 + wid * 64]);
      stage16(gB1 + (kt + 2) * 512, &ldsB[sb * 1024 + (wid + 8) * 64]);
      VM6B();
    } else if (kt + 1 < 32) {
      VM3B();
    } else {
      VM0B();
    }
    bf16x8 a_[4], b_[4];
#pragma unroll
    for (int i = 0; i < 4; ++i) a_[i] = ldsA[cb * 512 + (wr * 4 + i) * 64 + lane];
#pragma unroll
    for (int j = 0; j < 4; ++j) b_[j] = ldsB[cb * 1024 + (wc * 4 + j) * 64 + lane];
#pragma unroll
    for (int i = 0; i < 4; ++i)
#pragma unroll
      for (int j = 0; j < 4; ++j) acc[i][j] = mfma16(a_[i], b_[j], acc[i][j]);
    BAR();
  }

  if (!is_qk) {
    // ---- zT epilogue into chunked zT_c: elem (e,s) -> chunk (e>>4)*64+(s>>5),
    // off = ((s>>3)&3)*128 + (e&15)*8 + (s&7); v (s0..s0+3) contiguous, 8B aligned.
#pragma unroll
    for (int i = 0; i < 4; ++i) {
      const int s0 = mt * 128 + wr * 64 + i * 16 + lq * 4;
      const int s5 = s0 >> 5, s3 = (s0 >> 3) & 3, s7 = s0 & 7;
#pragma unroll
      for (int j = 0; j < 4; ++j) {
        const int e4 = ntl * 16 + wc * 4 + j;  // e>>4 (e&15 = lr)
        ushort4 o;
        o.x = f2b_bits(acc[i][j][0]); o.y = f2b_bits(acc[i][j][1]);
        o.z = f2b_bits(acc[i][j][2]); o.w = f2b_bits(acc[i][j][3]);
        *(ushort4*)(zT + ((size_t)b * 4096 + e4 * 64 + s5) * 512 + s3 * 128 + lr * 8 + s7) = o;
      }
    }
  } else {
    // ---- qk epilogue: exp, tri-packed chunked P, lsum atomics
    const int col128 = 2 * ct + (wc >> 1);
    if (col128 <= rt) {
      const bool diag = (col128 == rt);
      unsigned short* Pt =
          P + ((size_t)b * 136 + (size_t)(rt * (rt + 1) / 2 + col128)) * 16384;
      float* lsb = lsum + b * 2048 + rt * 128;
#pragma unroll
      for (int i = 0; i < 4; ++i) {
        const int row_l = wr * 64 + i * 16 + lq * 4;
        floatx4 rs = {0.0f, 0.0f, 0.0f, 0.0f};
#pragma unroll
        for (int j = 0; j < 4; ++j) {
          const int incol = (wc & 1) * 64 + j * 16 + lr;
          // chunk = (q>>4)*4 + (incol>>5); off = ((incol>>3)&3)*128 + (q&15)*8 + (incol&7)
          const int cbase = ((wr * 4 + i) * 4 + (wc & 1) * 2 + (j >> 1)) * 512 +
                            ((j * 2 + (lr >> 3)) & 3) * 128 + (lr & 7);
#pragma unroll
          for (int v = 0; v < 4; ++v) {
            float p = __expf(acc[i][j][v] * 0.03125f - 44.0f);
            if (diag && incol > row_l + v) p = 0.0f;
            Pt[cbase + (lq * 4 + v) * 8] = f2b_bits(p);
            rs[v] += p;
          }
        }
#pragma unroll
        for (int v = 0; v < 4; ++v) {
          float s = rs[v];
          s += __shfl_xor(s, 1);
          s += __shfl_xor(s, 2);
          s += __shfl_xor(s, 4);
          s += __shfl_xor(s, 8);
          if (lr == 0) atomicAdd(&lsb[row_l + v], s);
        }
      }
    }
  }
}

// ---------------------------------------------------------------- O = P @ z, divide by lsum
// 512 blocks = 1 round. Complementary pairing: blocks 0..255 get rt 15..8, blocks
// 256..511 get rt 0..7; pair (g, g+256) shares a CU (round-robin over 8 XCDs, 256%8=0)
// -> every CU runs rt1+rt2=15 => uniform 68 K-tiles/CU (was 40..96).
__global__ __launch_bounds__(512, 2) void pv_out(const unsigned short* __restrict__ P,
                                                 const unsigned short* __restrict__ zT,
                                                 const float* __restrict__ lsum,
                                                 float* __restrict__ out) {
  extern __shared__ bf16x8 lds[];
  bf16x8* ldsA = lds;
  bf16x8* ldsB = lds + 1536;
  const int tid = threadIdx.x, wid = tid >> 6, lane = tid & 63;
  const int wr = wid >> 2, wc = wid & 3, lr = lane & 15, lq = lane >> 4;
  const int g = blockIdx.x, b = g & 7, gg = g >> 3;
  const int q = gg >> 2;
  const int rt = (gg < 32) ? 15 - q : q - 8;
  const int ntl = gg & 3;
  const int NKT = (rt + 1) * 4;  // BK=32 tiles: 4..64

  // A: P tiles (tri-packed, chunked): kt -> tile tri+(kt>>2), chunk wid*4+(kt&3)
  const unsigned short* pA =
      P + ((size_t)b * 136 + (size_t)(rt * (rt + 1) / 2)) * 16384 + (size_t)wid * 2048 + lane * 8;
  // B: zT_c chunks (eblk = ntl*16 + w', sblk = kt)
  const unsigned short* gB0 = zT + ((size_t)b * 4096 + (ntl * 16 + wid) * 64) * 512 + lane * 8;
  const unsigned short* gB1 =
      zT + ((size_t)b * 4096 + (ntl * 16 + wid + 8) * 64) * 512 + lane * 8;
  floatx4 acc[4][4] = {};

#pragma unroll
  for (int t = 0; t < 2; ++t) {
    stage16(pA + (t >> 2) * 16384 + (t & 3) * 512, &ldsA[t * 512 + wid * 64]);
    stage16(gB0 + t * 512, &ldsB[t * 1024 + wid * 64]);
    stage16(gB1 + t * 512, &ldsB[t * 1024 + (wid + 8) * 64]);
  }

  int cb = 0, sb = 2;
  for (int kt = 0; kt < NKT; ++kt) {
    if (kt + 2 < NKT) {
      const int k2 = kt + 2;
      stage16(pA + (k2 >> 2) * 16384 + (k2 & 3) * 512, &ldsA[sb * 512 + wid * 64]);
      stage16(gB0 + k2 * 512, &ldsB[sb * 1024 + wid * 64]);
      stage16(gB1 + k2 * 512, &ldsB[sb * 1024 + (wid + 8) * 64]);
      VM6B();
    } else if (kt + 1 < NKT) {
      VM3B();
    } else {
      VM0B();
    }
    bf16x8 a_[4], b_[4];
#pragma unroll
    for (int i = 0; i < 4; ++i) a_[i] = ldsA[cb * 512 + (wr * 4 + i) * 64 + lane];
#pragma unroll
    for (int j = 0; j < 4; ++j) b_[j] = ldsB[cb * 1024 + (wc * 4 + j) * 64 + lane];
#pragma unroll
    for (int i = 0; i < 4; ++i)
#pragma unroll
      for (int j = 0; j < 4; ++j) acc[i][j] = mfma16(a_[i], b_[j], acc[i][j]);
    BAR();
    cb = (cb == 2) ? 0 : cb + 1;
    sb = (sb == 2) ? 0 : sb + 1;
  }

  const float* lsb = lsum + b * 2048 + rt * 128;
  float* outb = out + (size_t)b * 2097152;
#pragma unroll
  for (int i = 0; i < 4; ++i) {
    const int row_l = wr * 64 + i * 16 + lq * 4;
    floatx4 linv;
#pragma unroll
    for (int v = 0; v < 4; ++v) linv[v] = 1.0f / lsb[row_l + v];
#pragma unroll
    for (int j = 0; j < 4; ++j) {
      const int col = ntl * 256 + wc * 64 + j * 16 + lr;
#pragma unroll
      for (int v = 0; v < 4; ++v)
        __builtin_nontemporal_store(acc[i][j][v] * linv[v],
                                    &outb[(size_t)(rt * 128 + row_l + v) * 1024 + col]);
    }
  }
}

// ---------------------------------------------------------------- launcher
extern "C" void kernel_launch(void* const* d_in, const int* in_sizes, int n_in,
                              void* d_out, int out_size, void* d_ws, size_t ws_size,
                              hipStream_t stream) {
  const float* x = (const float*)d_in[0];  // [8][2048][1024]
  const float* W = (const float*)d_in[1];  // [1024][1024]
  float* out = (float*)d_out;              // [8][2048][1024]
  char* ws = (char*)d_ws;
  unsigned short* xb = (unsigned short*)ws;                          // 32 MiB chunked x
  unsigned short* zT = (unsigned short*)(ws + 33554432ull);          // 32 MiB chunked z^T
  unsigned short* P  = (unsigned short*)(ws + 67108864ull);          // 34 MiB tri P (chunked tiles)
  unsigned short* wb = (unsigned short*)(ws + 67108864ull + 35651584ull + 65536ull); // 2 MiB
  float* lsum = (float*)(ws + 67108864ull + 35651584ull);            // 64 KiB row sums

  static bool attr_done = false;
  if (!attr_done) {
    (void)hipFuncSetAttribute(reinterpret_cast<const void*>(zq_fused),
                              hipFuncAttributeMaxDynamicSharedMemorySize, 73728);
    (void)hipFuncSetAttribute(reinterpret_cast<const void*>(pv_out),
                              hipFuncAttributeMaxDynamicSharedMemorySize, 73728);
    attr_done = true;
  }

  cast_kernel<<<1092, 256, 0, stream>>>((const float4*)x, (const float4*)W,
                                        (uint4*)xb, (uint4*)wb, (float4*)lsum);
  zq_fused<<<1088, 512, 73728, stream>>>(xb, wb, zT, P, lsum);
  pv_out<<<512, 512, 73728, stream>>>(P, zT, lsum, out);
}